// Round 1
// baseline (238.898 us; speedup 1.0000x reference)
//
#include <hip/hip_runtime.h>
#include <math.h>

#define BN_EPS 0.001f
#define GEMM_BM 64

// ---------------- degree count ----------------
__global__ void k_count(const int2* __restrict__ ep, int ne, int* __restrict__ deg) {
  int e = blockIdx.x * blockDim.x + threadIdx.x;
  if (e < ne) {
    int2 p = ep[e];
    atomicAdd(&deg[p.x], 1);
  }
}

// ---------------- scan step 1: per-256-block sums ----------------
__global__ void k_blocksum(const int* __restrict__ deg, int n, int* __restrict__ bsum) {
  __shared__ int sdata[256];
  int t = threadIdx.x;
  int i = blockIdx.x * 256 + t;
  sdata[t] = (i < n) ? deg[i] : 0;
  __syncthreads();
  for (int s = 128; s > 0; s >>= 1) {
    if (t < s) sdata[t] += sdata[t + s];
    __syncthreads();
  }
  if (t == 0) bsum[blockIdx.x] = sdata[0];
}

// ---------------- scan step 2: single-block scan of block sums (nb <= 256) ----------------
__global__ void k_scan_bsums(const int* __restrict__ bsum, int nb, int* __restrict__ boff) {
  __shared__ int s0[256], s1[256];
  int t = threadIdx.x;
  int v = (t < nb) ? bsum[t] : 0;
  s0[t] = v;
  __syncthreads();
  int* src = s0; int* dst = s1;
  for (int off = 1; off < 256; off <<= 1) {
    int x = src[t];
    if (t >= off) x += src[t - off];
    dst[t] = x;
    __syncthreads();
    int* tmp = src; src = dst; dst = tmp;
  }
  if (t < nb) boff[t] = src[t] - v;  // exclusive
}

// ---------------- scan step 3: per-block exclusive scan + isd ----------------
__global__ void k_scan_final(const int* __restrict__ deg, int n, const int* __restrict__ boff,
                             int* __restrict__ offsets, int* __restrict__ cursor,
                             float* __restrict__ isd) {
  __shared__ int s0[256], s1[256];
  int t = threadIdx.x;
  int i = blockIdx.x * 256 + t;
  int v = (i < n) ? deg[i] : 0;
  s0[t] = v;
  __syncthreads();
  int* src = s0; int* dst = s1;
  for (int off = 1; off < 256; off <<= 1) {
    int x = src[t];
    if (t >= off) x += src[t - off];
    dst[t] = x;
    __syncthreads();
    int* tmp = src; src = dst; dst = tmp;
  }
  if (i < n) {
    int excl = src[t] - v + boff[blockIdx.x];
    offsets[i] = excl;
    cursor[i] = excl;
    // matches jnp.power(deg, -0.5): deg==0 -> +inf
    isd[i] = 1.0f / sqrtf((float)deg[i]);
  }
}

// ---------------- CSR fill ----------------
__global__ void k_fill(const int2* __restrict__ ep, int ne, int* __restrict__ cursor,
                       int* __restrict__ csr_dst) {
  int e = blockIdx.x * blockDim.x + threadIdx.x;
  if (e < ne) {
    int2 p = ep[e];
    int pos = atomicAdd(&cursor[p.x], 1);
    csr_dst[pos] = p.y;
  }
}

// ---------------- fp32 GEMM: T = X @ W + b  (M x 128 @ 128 x 128) ----------------
__global__ __launch_bounds__(256) void k_gemm(const float* __restrict__ X,
                                              const float* __restrict__ W,
                                              const float* __restrict__ b,
                                              float* __restrict__ T, int M) {
  constexpr int LDA = 68;   // As[k][row], k in [0,64), padded stride (16B-aligned rows)
  constexpr int LDW = 132;  // Ws[k][col], padded stride
  __shared__ float As[64 * LDA];
  __shared__ float Ws[64 * LDW];
  int tid = threadIdx.x;
  int brow = blockIdx.x * GEMM_BM;
  int rows_here = M - brow;
  if (rows_here > GEMM_BM) rows_here = GEMM_BM;
  int tx = tid & 15;   // col group: cols tx*8 .. +7
  int ty = tid >> 4;   // row group: rows ty*4 .. +3
  float acc[4][8] = {};
  for (int kt = 0; kt < 2; ++kt) {
    __syncthreads();  // protect LDS from previous chunk's readers
    // load W chunk: rows kt*64 .. +63, all 128 cols
    for (int idx = tid; idx < 64 * 32; idx += 256) {
      int k = idx >> 5;
      int c4 = idx & 31;
      float4 v = ((const float4*)(W + ((kt * 64 + k) << 7)))[c4];
      *(float4*)&Ws[k * LDW + c4 * 4] = v;
    }
    // load A chunk (transposed into LDS): rows brow..+63, k = kt*64..+63
    for (int idx = tid; idx < 64 * 16; idx += 256) {
      int r = idx >> 4;
      int kq = idx & 15;
      float4 v = make_float4(0.f, 0.f, 0.f, 0.f);
      if (r < rows_here)
        v = ((const float4*)(X + (((size_t)(brow + r)) << 7) + kt * 64))[kq];
      As[(kq * 4 + 0) * LDA + r] = v.x;
      As[(kq * 4 + 1) * LDA + r] = v.y;
      As[(kq * 4 + 2) * LDA + r] = v.z;
      As[(kq * 4 + 3) * LDA + r] = v.w;
    }
    __syncthreads();
#pragma unroll 8
    for (int k = 0; k < 64; ++k) {
      float4 av = *(const float4*)&As[k * LDA + ty * 4];
      float4 w0 = *(const float4*)&Ws[k * LDW + tx * 8];
      float4 w1 = *(const float4*)&Ws[k * LDW + tx * 8 + 4];
      float a[4] = {av.x, av.y, av.z, av.w};
      float w[8] = {w0.x, w0.y, w0.z, w0.w, w1.x, w1.y, w1.z, w1.w};
#pragma unroll
      for (int r = 0; r < 4; ++r)
#pragma unroll
        for (int c = 0; c < 8; ++c)
          acc[r][c] = fmaf(a[r], w[c], acc[r][c]);
    }
  }
  float4 b0 = ((const float4*)b)[tx * 2];
  float4 b1 = ((const float4*)b)[tx * 2 + 1];
  float bias[8] = {b0.x, b0.y, b0.z, b0.w, b1.x, b1.y, b1.z, b1.w};
  for (int r = 0; r < 4; ++r) {
    int row = brow + ty * 4 + r;
    if (row < M) {
      float4 o0 = make_float4(acc[r][0] + bias[0], acc[r][1] + bias[1],
                              acc[r][2] + bias[2], acc[r][3] + bias[3]);
      float4 o1 = make_float4(acc[r][4] + bias[4], acc[r][5] + bias[5],
                              acc[r][6] + bias[6], acc[r][7] + bias[7]);
      float* dst = T + (((size_t)row) << 7) + tx * 8;
      *(float4*)dst = o0;
      *(float4*)(dst + 4) = o1;
    }
  }
}

// ---------------- gather neighbors + fused BN epilogue ----------------
__global__ __launch_bounds__(128) void k_gather(
    const float* __restrict__ T, const int* __restrict__ deg,
    const float* __restrict__ isd, const int* __restrict__ offsets,
    const int* __restrict__ csr_dst,
    const float* __restrict__ mm, const float* __restrict__ var,
    const float* __restrict__ gamma, const float* __restrict__ beta,
    float* __restrict__ out, int n) {
  int i = blockIdx.x;
  int j = threadIdx.x;
  int degi = deg[i];
  int start = offsets[i];
  float s = 0.f;
  for (int e = 0; e < degi; ++e) {
    int d = csr_dst[start + e];
    s += T[((size_t)d << 7) + j] * isd[d];
  }
  float agg = 0.f;
  if (degi > 0) {
    float nb = isd[i] * s;                                 // nb_sum
    float sm = (float)degi * T[((size_t)i << 7) + j];      // src_mean = deg * t
    agg = 0.5f * nb + 0.5f * sm;
  }
  out[((size_t)i << 7) + j] =
      (agg - mm[j]) * rsqrtf(var[j] + BN_EPS) * gamma[j] + beta[j];
}

static inline size_t align_up(size_t x) { return (x + 255) & ~(size_t)255; }

extern "C" void kernel_launch(void* const* d_in, const int* in_sizes, int n_in,
                              void* d_out, int out_size, void* d_ws, size_t ws_size,
                              hipStream_t stream) {
  const int2* ep = (const int2*)d_in[0];
  const float* X = (const float*)d_in[1];
  const float* W = (const float*)d_in[2];
  const float* b = (const float*)d_in[3];
  const float* gamma = (const float*)d_in[4];
  const float* beta = (const float*)d_in[5];
  const float* mm = (const float*)d_in[6];
  const float* var = (const float*)d_in[7];
  float* out = (float*)d_out;

  const int ne = in_sizes[0] / 2;
  const int n = in_sizes[1] / 128;
  const int nblk = (n + 255) / 256;  // 196 for n=50000; must be <= 256

  char* p = (char*)d_ws;
  int* deg = (int*)p;       p += align_up((size_t)n * 4);
  float* isd = (float*)p;   p += align_up((size_t)n * 4);
  int* offsets = (int*)p;   p += align_up((size_t)n * 4);
  int* cursor = (int*)p;    p += align_up((size_t)n * 4);
  int* bsum = (int*)p;      p += align_up((size_t)nblk * 4);
  int* boff = (int*)p;      p += align_up((size_t)nblk * 4);
  int* csr_dst = (int*)p;   p += align_up((size_t)ne * 4);
  float* T = (float*)p;     p += align_up((size_t)n * 128 * 4);

  hipMemsetAsync(deg, 0, (size_t)n * 4, stream);
  k_count<<<(ne + 255) / 256, 256, 0, stream>>>(ep, ne, deg);
  k_blocksum<<<nblk, 256, 0, stream>>>(deg, n, bsum);
  k_scan_bsums<<<1, 256, 0, stream>>>(bsum, nblk, boff);
  k_scan_final<<<nblk, 256, 0, stream>>>(deg, n, boff, offsets, cursor, isd);
  k_fill<<<(ne + 255) / 256, 256, 0, stream>>>(ep, ne, cursor, csr_dst);
  k_gemm<<<(n + GEMM_BM - 1) / GEMM_BM, 256, 0, stream>>>(X, W, b, T, n);
  k_gather<<<n, 128, 0, stream>>>(T, deg, isd, offsets, csr_dst, mm, var, gamma, beta, out, n);
}

// Round 2
// 178.122 us; speedup vs baseline: 1.3412x; 1.3412x over previous
//
#include <hip/hip_runtime.h>
#include <math.h>

#define BN_EPS 0.001f
#define GEMM_BM 64

__device__ inline unsigned bf16rne(float f) {
  unsigned u = __float_as_uint(f);
  return (u + 0x7fffu + ((u >> 16) & 1u)) >> 16;
}
__device__ inline float bflo(unsigned r) { return __uint_as_float(r << 16); }
__device__ inline float bfhi(unsigned r) { return __uint_as_float(r & 0xffff0000u); }

// ---------------- degree count (2 edges/thread) ----------------
__global__ void k_count(const int4* __restrict__ ep2, int ne, int* __restrict__ deg) {
  int h = blockIdx.x * blockDim.x + threadIdx.x;
  if (2 * h < ne) {
    int4 p = ep2[h];
    atomicAdd(&deg[p.x], 1);
    if (2 * h + 1 < ne) atomicAdd(&deg[p.z], 1);
  }
}

// ---------------- scan step 1: per-256-block sums ----------------
__global__ void k_blocksum(const int* __restrict__ deg, int n, int* __restrict__ bsum) {
  __shared__ int sdata[256];
  int t = threadIdx.x;
  int i = blockIdx.x * 256 + t;
  sdata[t] = (i < n) ? deg[i] : 0;
  __syncthreads();
  for (int s = 128; s > 0; s >>= 1) {
    if (t < s) sdata[t] += sdata[t + s];
    __syncthreads();
  }
  if (t == 0) bsum[blockIdx.x] = sdata[0];
}

// ---------------- scan step 2: single-block scan of block sums (nb <= 256) ----------------
__global__ void k_scan_bsums(const int* __restrict__ bsum, int nb, int* __restrict__ boff) {
  __shared__ int s0[256], s1[256];
  int t = threadIdx.x;
  int v = (t < nb) ? bsum[t] : 0;
  s0[t] = v;
  __syncthreads();
  int* src = s0; int* dst = s1;
  for (int off = 1; off < 256; off <<= 1) {
    int x = src[t];
    if (t >= off) x += src[t - off];
    dst[t] = x;
    __syncthreads();
    int* tmp = src; src = dst; dst = tmp;
  }
  if (t < nb) boff[t] = src[t] - v;  // exclusive
}

// ---------------- scan step 3: per-block exclusive scan + isd ----------------
__global__ void k_scan_final(const int* __restrict__ deg, int n, const int* __restrict__ boff,
                             int* __restrict__ offsets, int* __restrict__ cursor,
                             float* __restrict__ isd) {
  __shared__ int s0[256], s1[256];
  int t = threadIdx.x;
  int i = blockIdx.x * 256 + t;
  int v = (i < n) ? deg[i] : 0;
  s0[t] = v;
  __syncthreads();
  int* src = s0; int* dst = s1;
  for (int off = 1; off < 256; off <<= 1) {
    int x = src[t];
    if (t >= off) x += src[t - off];
    dst[t] = x;
    __syncthreads();
    int* tmp = src; src = dst; dst = tmp;
  }
  if (i < n) {
    int excl = src[t] - v + boff[blockIdx.x];
    offsets[i] = excl;
    cursor[i] = excl;
    isd[i] = 1.0f / sqrtf((float)deg[i]);  // deg==0 -> +inf, matches jnp.power
  }
}

// ---------------- CSR fill (2 edges/thread) ----------------
__global__ void k_fill(const int4* __restrict__ ep2, int ne, int* __restrict__ cursor,
                       int* __restrict__ csr_dst) {
  int h = blockIdx.x * blockDim.x + threadIdx.x;
  if (2 * h < ne) {
    int4 p = ep2[h];
    int pos = atomicAdd(&cursor[p.x], 1);
    csr_dst[pos] = p.y;
    if (2 * h + 1 < ne) {
      int pos2 = atomicAdd(&cursor[p.z], 1);
      csr_dst[pos2] = p.w;
    }
  }
}

// ---------------- fp32 GEMM: T = X @ W + b, also emits bf16-packed Tb ----------------
__global__ __launch_bounds__(256) void k_gemm(const float* __restrict__ X,
                                              const float* __restrict__ W,
                                              const float* __restrict__ b,
                                              float* __restrict__ T,
                                              unsigned* __restrict__ Tb, int M) {
  constexpr int LDA = 68;
  constexpr int LDW = 132;
  __shared__ float As[64 * LDA];
  __shared__ float Ws[64 * LDW];
  int tid = threadIdx.x;
  int brow = blockIdx.x * GEMM_BM;
  int rows_here = M - brow;
  if (rows_here > GEMM_BM) rows_here = GEMM_BM;
  int tx = tid & 15;   // cols tx*8 .. +7
  int ty = tid >> 4;   // rows ty*4 .. +3
  float acc[4][8] = {};
  for (int kt = 0; kt < 2; ++kt) {
    __syncthreads();
    for (int idx = tid; idx < 64 * 32; idx += 256) {
      int k = idx >> 5;
      int c4 = idx & 31;
      float4 v = ((const float4*)(W + ((kt * 64 + k) << 7)))[c4];
      *(float4*)&Ws[k * LDW + c4 * 4] = v;
    }
    for (int idx = tid; idx < 64 * 16; idx += 256) {
      int r = idx >> 4;
      int kq = idx & 15;
      float4 v = make_float4(0.f, 0.f, 0.f, 0.f);
      if (r < rows_here)
        v = ((const float4*)(X + (((size_t)(brow + r)) << 7) + kt * 64))[kq];
      As[(kq * 4 + 0) * LDA + r] = v.x;
      As[(kq * 4 + 1) * LDA + r] = v.y;
      As[(kq * 4 + 2) * LDA + r] = v.z;
      As[(kq * 4 + 3) * LDA + r] = v.w;
    }
    __syncthreads();
#pragma unroll 8
    for (int k = 0; k < 64; ++k) {
      float4 av = *(const float4*)&As[k * LDA + ty * 4];
      float4 w0 = *(const float4*)&Ws[k * LDW + tx * 8];
      float4 w1 = *(const float4*)&Ws[k * LDW + tx * 8 + 4];
      float a[4] = {av.x, av.y, av.z, av.w};
      float w[8] = {w0.x, w0.y, w0.z, w0.w, w1.x, w1.y, w1.z, w1.w};
#pragma unroll
      for (int r = 0; r < 4; ++r)
#pragma unroll
        for (int c = 0; c < 8; ++c)
          acc[r][c] = fmaf(a[r], w[c], acc[r][c]);
    }
  }
  float4 b0 = ((const float4*)b)[tx * 2];
  float4 b1 = ((const float4*)b)[tx * 2 + 1];
  float bias[8] = {b0.x, b0.y, b0.z, b0.w, b1.x, b1.y, b1.z, b1.w};
  for (int r = 0; r < 4; ++r) {
    int row = brow + ty * 4 + r;
    if (row < M) {
      float o[8];
#pragma unroll
      for (int c = 0; c < 8; ++c) o[c] = acc[r][c] + bias[c];
      float* dst = T + (((size_t)row) << 7) + tx * 8;
      *(float4*)dst = make_float4(o[0], o[1], o[2], o[3]);
      *(float4*)(dst + 4) = make_float4(o[4], o[5], o[6], o[7]);
      // bf16 packed copy: 4 dwords (8 cols)
      unsigned pk[4];
#pragma unroll
      for (int c = 0; c < 4; ++c)
        pk[c] = bf16rne(o[2 * c]) | (bf16rne(o[2 * c + 1]) << 16);
      *(uint4*)(Tb + (((size_t)row) << 6) + tx * 4) =
          make_uint4(pk[0], pk[1], pk[2], pk[3]);
    }
  }
}

// ---------------- gather: one wave per node, bf16 neighbor rows ----------------
__global__ __launch_bounds__(256) void k_gather(
    const float* __restrict__ T, const unsigned* __restrict__ Tb,
    const int* __restrict__ deg, const float* __restrict__ isd,
    const int* __restrict__ offsets, const int* __restrict__ csr_dst,
    const float* __restrict__ mm, const float* __restrict__ var,
    const float* __restrict__ gamma, const float* __restrict__ beta,
    float* __restrict__ out, int n) {
  int wave = threadIdx.x >> 6;
  int lane = threadIdx.x & 63;
  int i = blockIdx.x * 4 + wave;
  if (i >= n) return;
  int degi = deg[i];
  int start = offsets[i];
  float sx0 = 0.f, sy0 = 0.f, sx1 = 0.f, sy1 = 0.f;
  float sx2 = 0.f, sy2 = 0.f, sx3 = 0.f, sy3 = 0.f;
  int e = 0;
  for (; e + 4 <= degi; e += 4) {
    int d0 = csr_dst[start + e];
    int d1 = csr_dst[start + e + 1];
    int d2 = csr_dst[start + e + 2];
    int d3 = csr_dst[start + e + 3];
    unsigned r0 = Tb[((size_t)d0 << 6) + lane];
    unsigned r1 = Tb[((size_t)d1 << 6) + lane];
    unsigned r2 = Tb[((size_t)d2 << 6) + lane];
    unsigned r3 = Tb[((size_t)d3 << 6) + lane];
    float is0 = isd[d0], is1 = isd[d1], is2 = isd[d2], is3 = isd[d3];
    sx0 = fmaf(bflo(r0), is0, sx0); sy0 = fmaf(bfhi(r0), is0, sy0);
    sx1 = fmaf(bflo(r1), is1, sx1); sy1 = fmaf(bfhi(r1), is1, sy1);
    sx2 = fmaf(bflo(r2), is2, sx2); sy2 = fmaf(bfhi(r2), is2, sy2);
    sx3 = fmaf(bflo(r3), is3, sx3); sy3 = fmaf(bfhi(r3), is3, sy3);
  }
  for (; e < degi; ++e) {
    int d = csr_dst[start + e];
    unsigned r = Tb[((size_t)d << 6) + lane];
    float is = isd[d];
    sx0 = fmaf(bflo(r), is, sx0);
    sy0 = fmaf(bfhi(r), is, sy0);
  }
  float sx = (sx0 + sx1) + (sx2 + sx3);
  float sy = (sy0 + sy1) + (sy2 + sy3);
  float aggx = 0.f, aggy = 0.f;
  if (degi > 0) {
    float2 tv = ((const float2*)(T + ((size_t)i << 7)))[lane];
    float isi = isd[i];
    float di = (float)degi;
    aggx = 0.5f * (isi * sx) + 0.5f * (di * tv.x);
    aggy = 0.5f * (isi * sy) + 0.5f * (di * tv.y);
  }
  float2 mmv = ((const float2*)mm)[lane];
  float2 vv = ((const float2*)var)[lane];
  float2 gv = ((const float2*)gamma)[lane];
  float2 bv = ((const float2*)beta)[lane];
  float2 res;
  res.x = (aggx - mmv.x) * rsqrtf(vv.x + BN_EPS) * gv.x + bv.x;
  res.y = (aggy - mmv.y) * rsqrtf(vv.y + BN_EPS) * gv.y + bv.y;
  ((float2*)(out + ((size_t)i << 7)))[lane] = res;
}

static inline size_t align_up(size_t x) { return (x + 255) & ~(size_t)255; }

extern "C" void kernel_launch(void* const* d_in, const int* in_sizes, int n_in,
                              void* d_out, int out_size, void* d_ws, size_t ws_size,
                              hipStream_t stream) {
  const int4* ep2 = (const int4*)d_in[0];
  const float* X = (const float*)d_in[1];
  const float* W = (const float*)d_in[2];
  const float* b = (const float*)d_in[3];
  const float* gamma = (const float*)d_in[4];
  const float* beta = (const float*)d_in[5];
  const float* mm = (const float*)d_in[6];
  const float* var = (const float*)d_in[7];
  float* out = (float*)d_out;

  const int ne = in_sizes[0] / 2;
  const int n = in_sizes[1] / 128;
  const int nblk = (n + 255) / 256;

  char* p = (char*)d_ws;
  int* deg = (int*)p;        p += align_up((size_t)n * 4);
  float* isd = (float*)p;    p += align_up((size_t)n * 4);
  int* offsets = (int*)p;    p += align_up((size_t)n * 4);
  int* cursor = (int*)p;     p += align_up((size_t)n * 4);
  int* bsum = (int*)p;       p += align_up((size_t)nblk * 4);
  int* boff = (int*)p;       p += align_up((size_t)nblk * 4);
  int* csr_dst = (int*)p;    p += align_up((size_t)ne * 4);
  float* T = (float*)p;      p += align_up((size_t)n * 128 * 4);
  unsigned* Tb = (unsigned*)p; p += align_up((size_t)n * 64 * 4);

  hipMemsetAsync(deg, 0, (size_t)n * 4, stream);
  int nh = (ne + 1) / 2;
  k_count<<<(nh + 255) / 256, 256, 0, stream>>>(ep2, ne, deg);
  k_blocksum<<<nblk, 256, 0, stream>>>(deg, n, bsum);
  k_scan_bsums<<<1, 256, 0, stream>>>(bsum, nblk, boff);
  k_scan_final<<<nblk, 256, 0, stream>>>(deg, n, boff, offsets, cursor, isd);
  k_fill<<<(nh + 255) / 256, 256, 0, stream>>>(ep2, ne, cursor, csr_dst);
  k_gemm<<<(n + GEMM_BM - 1) / GEMM_BM, 256, 0, stream>>>(X, W, b, T, Tb, n);
  k_gather<<<(n + 3) / 4, 256, 0, stream>>>(T, Tb, deg, isd, offsets, csr_dst,
                                            mm, var, gamma, beta, out, n);
}